// Round 3
// baseline (374.255 us; speedup 1.0000x reference)
//
#include <hip/hip_runtime.h>
#include <hip/hip_bf16.h>

// DirNet: out[k,o,idx[j],d] = SCALE * sum_i x[k,o,idx[j],i] * W[o,d,i] + b[o,d]
// Batched B^T GEMM, bf16 MFMA (16x16x32), fp32 accumulate.
// R9: de-risked retreat after two container failures on the R7 single-barrier
// double-buffer. Sync skeleton reverted to the harness-PROVEN R6 schedule
// (single LDS buffer pair, TWO relaxed barriers per K-iter, 20 KiB LDS).
// Kept from R7 (both sync-structure-neutral):
//  - B register prefetch depth 1 -> 2 (symmetric with A): B's cvt wait gains
//    a full extra iteration (~350 cy) of vmcnt slack at the iter-top convoy.
//  - j-dense XCD swizzle: concurrent same-XCD blocks walk (mt,j) contiguously
//    within one o -> dense 36 KB x-windows + W[o] L2 reuse per XCD.
// New hardening: compiler memory-clobber fences around the relaxed barrier so
// LLVM cannot reorder ds_read/ds_write across s_barrier (raw s_barrier is not
// an IR-level memory fence; R6 relied on the compiler not reordering).

typedef __bf16  bf16x8  __attribute__((ext_vector_type(8)));
typedef float   floatx4 __attribute__((ext_vector_type(4)));

#define O_DIM 18
#define J_DIM 18
#define KB    256
#define C_DIM 512
#define BM    128
#define BN    128
#define BK    32
#define NK    (C_DIM / BK)   // 16 K-iterations
#define LDSS  40             // BK + 8 pad -> 80B stride, 2-way-free b128 reads

__device__ __forceinline__ __bf16 f2bf(float f) { return (__bf16)f; }

// Barrier that waits only LDS ops (lgkmcnt(0)), leaving global loads (vmcnt)
// in flight. 0xc07f = vmcnt 63 | expcnt 7 | lgkmcnt 0 (gfx9 encoding).
// Memory clobbers pin LDS op ordering across the barrier at compile time.
__device__ __forceinline__ void barrier_lds() {
    asm volatile("" ::: "memory");
    __builtin_amdgcn_s_waitcnt(0xc07f);
    __builtin_amdgcn_s_barrier();
    asm volatile("" ::: "memory");
}

__global__ __launch_bounds__(256, 2)
void dirnet_gemm(const float* __restrict__ x, const float* __restrict__ W,
                 const float* __restrict__ bias, const int* __restrict__ idx,
                 float* __restrict__ out)
{
    // XCD-aware decode. 2592 blocks = 8 XCD x 324. Round-robin dispatch puts
    // id&7 on one XCD. Per-XCD rank r: nt cycles fastest (4 nt-siblings share
    // one A-tile -> co-XCD L2), then the stream walks T = xcd*81 + q over
    // (o, j, mt) with mt fastest, then j -> adjacent j's concurrent per XCD.
    // Bijective: 8*81 = 648 = 18*18*2.
    const int id  = blockIdx.x;        // 0..2591
    const int xcd = id & 7;
    const int r   = id >> 3;           // 0..323
    const int nt  = r & 3;
    const int q   = r >> 2;            // 0..80
    const int T   = xcd * 81 + q;      // 0..647, bijective
    const int o   = T / 36;
    const int rem = T - o * 36;
    const int j   = rem >> 1;
    const int mt  = rem & 1;
    const int jj  = idx[j];

    __shared__ __bf16 As[BM * LDSS];   // 10240 B
    __shared__ __bf16 Bs[BN * LDSS];   // 10240 B

    const int tid  = threadIdx.x;
    const int srow = tid >> 2;          // 0..63
    const int scol = (tid & 3) << 3;    // 0,8,16,24

    const float* xp = x + ((size_t)((mt * BM + srow) * O_DIM + o) * J_DIM + jj) * C_DIM + scol;
    const size_t xRS = (size_t)64 * O_DIM * J_DIM * C_DIM;
    const float* wp = W + ((size_t)(o * C_DIM + nt * BN + srow)) * C_DIM + scol;
    const size_t wRS = (size_t)64 * C_DIM;

    const int lane = tid & 63;
    const int wv   = tid >> 6;
    const int mOff = (wv & 1) * 64;
    const int nOff = (wv >> 1) * 64;
    const int lrow = lane & 15;         // frag row (A: m, B: n)
    const int lk   = (lane >> 4) << 3;  // frag k offset (quad*8)

    floatx4 acc[4][4] = {};
    float4 pa[2][2][2];   // [set][row-half][float4-half]  A: depth-2
    float4 pb[2][2][2];   // [set][row-half][float4-half]  B: depth-2

#define LOAD_A(set, kk)                                                \
    {                                                                  \
        _Pragma("unroll")                                              \
        for (int p = 0; p < 2; ++p) {                                  \
            pa[set][p][0] = *(const float4*)(xp + p * xRS + (kk));     \
            pa[set][p][1] = *(const float4*)(xp + p * xRS + (kk) + 4); \
        }                                                              \
    }
#define LOAD_B(set, kk)                                                \
    {                                                                  \
        _Pragma("unroll")                                              \
        for (int p = 0; p < 2; ++p) {                                  \
            pb[set][p][0] = *(const float4*)(wp + p * wRS + (kk));     \
            pb[set][p][1] = *(const float4*)(wp + p * wRS + (kk) + 4); \
        }                                                              \
    }
#define CVT_AB(set, sa, sb)                                                   \
    {                                                                         \
        _Pragma("unroll")                                                     \
        for (int p = 0; p < 2; ++p) {                                         \
            sa[p][0]=f2bf(pa[set][p][0].x); sa[p][1]=f2bf(pa[set][p][0].y);   \
            sa[p][2]=f2bf(pa[set][p][0].z); sa[p][3]=f2bf(pa[set][p][0].w);   \
            sa[p][4]=f2bf(pa[set][p][1].x); sa[p][5]=f2bf(pa[set][p][1].y);   \
            sa[p][6]=f2bf(pa[set][p][1].z); sa[p][7]=f2bf(pa[set][p][1].w);   \
        }                                                                     \
        _Pragma("unroll")                                                     \
        for (int p = 0; p < 2; ++p) {                                         \
            sb[p][0]=f2bf(pb[set][p][0].x); sb[p][1]=f2bf(pb[set][p][0].y);   \
            sb[p][2]=f2bf(pb[set][p][0].z); sb[p][3]=f2bf(pb[set][p][0].w);   \
            sb[p][4]=f2bf(pb[set][p][1].x); sb[p][5]=f2bf(pb[set][p][1].y);   \
            sb[p][6]=f2bf(pb[set][p][1].z); sb[p][7]=f2bf(pb[set][p][1].w);   \
        }                                                                     \
    }
#define STORE_AB(sa, sb)                                               \
    {                                                                  \
        _Pragma("unroll")                                              \
        for (int p = 0; p < 2; ++p) {                                  \
            *(bf16x8*)&As[(p * 64 + srow) * LDSS + scol] = sa[p];      \
            *(bf16x8*)&Bs[(p * 64 + srow) * LDSS + scol] = sb[p];      \
        }                                                              \
    }

    // ---- Prologue: tiles 0,1 -> reg sets 0,1 (issue order = consume order)
    LOAD_A(0, 0);       LOAD_B(0, 0);
    LOAD_A(1, BK);      LOAD_B(1, BK);

    // ---- Main loop: R6-proven schedule, two relaxed barriers per iter ----
    #pragma unroll
    for (int t = 0; t < NK; ++t) {
        const int s = t & 1;

        // Convert tile t (both operands prefetched 2 iters ago; the implicit
        // vmcnt wait here leaves the younger tile-(t+1) loads in flight).
        bf16x8 sa[2], sb[2];
        CVT_AB(s, sa, sb);

        barrier_lds();   // all waves' prior frag ds_reads retired (lgkmcnt 0)
        STORE_AB(sa, sb);
        barrier_lds();   // staged tile visible; vmcnt prefetches NOT drained

        // Refill the just-consumed register set with tile t+2 (consumed at
        // iter t+2 -> ~2 iterations in flight, never drained by barriers).
        if (t + 2 < NK) {
            const int k2 = (t + 2) * BK;
            LOAD_A(s, k2);
            LOAD_B(s, k2);
        }

        bf16x8 af[4], bfr[4];
        #pragma unroll
        for (int mi = 0; mi < 4; ++mi)
            af[mi] = *(const bf16x8*)&As[(mOff + mi * 16 + lrow) * LDSS + lk];
        #pragma unroll
        for (int ni = 0; ni < 4; ++ni)
            bfr[ni] = *(const bf16x8*)&Bs[(nOff + ni * 16 + lrow) * LDSS + lk];

        #pragma unroll
        for (int mi = 0; mi < 4; ++mi)
            #pragma unroll
            for (int ni = 0; ni < 4; ++ni)
                acc[mi][ni] = __builtin_amdgcn_mfma_f32_16x16x32_bf16(
                    af[mi], bfr[ni], acc[mi][ni], 0, 0, 0);
    }

#undef LOAD_A
#undef LOAD_B
#undef CVT_AB
#undef STORE_AB

    // Epilogue: C/D layout col = lane&15 (n), row = (lane>>4)*4 + r (m)
    const float scale = 0.04419417382415922f;  // 1/sqrt(512), LR_MUL = 1
    const int rbase = (lane >> 4) << 2;
    #pragma unroll
    for (int ni = 0; ni < 4; ++ni) {
        const int d  = nt * BN + nOff + ni * 16 + lrow;
        const float bv = bias[o * C_DIM + d];
        #pragma unroll
        for (int mi = 0; mi < 4; ++mi) {
            #pragma unroll
            for (int r2 = 0; r2 < 4; ++r2) {
                const int kr = mt * BM + mOff + mi * 16 + rbase + r2;
                out[((size_t)(kr * O_DIM + o) * J_DIM + jj) * C_DIM + d] =
                    acc[mi][ni][r2] * scale + bv;
            }
        }
    }
}

// Rows jj not present in idx keep their x values. With idx = arange(18) this
// kernel does no memory traffic (membership always true -> early exit).
__global__ void copy_nonsel(const float* __restrict__ x, const int* __restrict__ idx,
                            float* __restrict__ out)
{
    const int jj = blockIdx.x;
    const int o  = blockIdx.y;
    bool member = false;
    for (int t = 0; t < J_DIM; ++t) member = member || (idx[t] == jj);
    if (member) return;
    const int tid = threadIdx.x;
    for (int k = 0; k < KB; ++k) {
        const size_t base = ((size_t)(k * O_DIM + o) * J_DIM + jj) * C_DIM;
        for (int c = tid * 4; c < C_DIM; c += 256 * 4) {
            *(float4*)&out[base + c] = *(const float4*)&x[base + c];
        }
    }
}

extern "C" void kernel_launch(void* const* d_in, const int* in_sizes, int n_in,
                              void* d_out, int out_size, void* d_ws, size_t ws_size,
                              hipStream_t stream) {
    const float* x   = (const float*)d_in[0];
    const float* W   = (const float*)d_in[1];
    const float* b   = (const float*)d_in[2];
    const int*   idx = (const int*)d_in[3];
    float* out = (float*)d_out;

    // 2 mt * 4 nt * 18 j * 18 o = 2592 blocks
    dirnet_gemm<<<dim3(2 * 4 * J_DIM * O_DIM), 256, 0, stream>>>(x, W, b, idx, out);
    copy_nonsel<<<dim3(J_DIM, O_DIM), 256, 0, stream>>>(x, idx, out);
}

// Round 4
// 371.286 us; speedup vs baseline: 1.0080x; 1.0080x over previous
//
#include <hip/hip_runtime.h>
#include <hip/hip_bf16.h>

// DirNet: out[k,o,idx[j],d] = SCALE * sum_i x[k,o,idx[j],i] * W[o,d,i] + b[o,d]
// Batched B^T GEMM, bf16 MFMA (16x16x32), fp32 accumulate.
// R10: logical-traffic attack. R9 post-mortem showed FETCH 205->113MB with
// time WORSE -> not HBM-bound; bound by L2/L3 service of LOGICAL reads
// (1.36 GB = x*4(nt) + W*36(mt*j) redundancy; ~14 B/cy/CU L2 share matches
// the measured ~6-7k cy/iteration with MFMA/VALU/HBM all idle).
// Fix: 256x256 tile halves logical traffic (680 MB): x redundancy 4->2,
// W redundancy 36->18. 512 threads / 8 waves (2Mx4N), wave tile 128x64,
// BK=32, and the harness-PROVEN R6 2-barrier relaxed schedule unchanged.
// A prefetch depth-2 (x is far: L3/HBM), B depth-1 (W is L2-hot).
// Grid 648 = 18o x 18j x 2nt, XCD swizzle nt-fastest then j-dense.

typedef __bf16  bf16x8  __attribute__((ext_vector_type(8)));
typedef float   floatx4 __attribute__((ext_vector_type(4)));

#define O_DIM 18
#define J_DIM 18
#define KB    256
#define C_DIM 512
#define BM    256
#define BN    256
#define BK    32
#define NK    (C_DIM / BK)   // 16 K-iterations
#define LDSS  40             // BK + 8 pad -> 80B stride, 2-way-free b128 reads

__device__ __forceinline__ __bf16 f2bf(float f) { return (__bf16)f; }

// Barrier that waits only LDS ops (lgkmcnt(0)), leaving global loads (vmcnt)
// in flight. 0xc07f = vmcnt 63 | expcnt 7 | lgkmcnt 0 (gfx9 encoding).
// Memory clobbers pin LDS op ordering across the barrier at compile time.
__device__ __forceinline__ void barrier_lds() {
    asm volatile("" ::: "memory");
    __builtin_amdgcn_s_waitcnt(0xc07f);
    __builtin_amdgcn_s_barrier();
    asm volatile("" ::: "memory");
}

__global__ __launch_bounds__(512, 2)
void dirnet_gemm(const float* __restrict__ x, const float* __restrict__ W,
                 const float* __restrict__ bias, const int* __restrict__ idx,
                 float* __restrict__ out)
{
    // XCD-aware decode. 648 blocks = 8 XCD x 81. Round-robin dispatch puts
    // id&7 on one XCD. Per-XCD rank q walks T = xcd*81 + q over (o, j, nt)
    // with nt fastest (nt-pair shares the x A-tile -> co-XCD L2 reuse),
    // then j (adjacent j concurrent per XCD -> dense x windows + W[o] reuse).
    // Bijective: 8*81 = 648 = 18*18*2.
    const int id  = blockIdx.x;        // 0..647
    const int xcd = id & 7;
    const int q   = id >> 3;           // 0..80
    const int T   = xcd * 81 + q;      // 0..647, bijective
    const int o   = T / 36;
    const int rem = T - o * 36;
    const int j   = rem >> 1;
    const int nt  = rem & 1;
    const int jj  = idx[j];

    __shared__ __bf16 As[BM * LDSS];   // 20480 B
    __shared__ __bf16 Bs[BN * LDSS];   // 20480 B

    const int tid  = threadIdx.x;
    const int srow = tid >> 1;          // 0..255 (tile row; A: k, B: d)
    const int scol = (tid & 1) << 4;    // 0 or 16 (float col within K-window)

    // A row srow = batch index k = srow; column = C-dim.
    const float* xp = x + ((size_t)(srow * O_DIM + o) * J_DIM + jj) * C_DIM + scol;
    // B row srow = output dim d = nt*256 + srow; column = C-dim.
    const float* wp = W + ((size_t)(o * C_DIM + nt * BN + srow)) * C_DIM + scol;

    const int lane = tid & 63;
    const int wv   = tid >> 6;          // 0..7 waves, 2(M) x 4(N)
    const int mOff = (wv & 1) * 128;
    const int nOff = (wv >> 1) * 64;
    const int lrow = lane & 15;         // frag row (A: m, B: n)
    const int lk   = (lane >> 4) << 3;  // frag k offset (quad*8)

    floatx4 acc[8][4] = {};   // wave tile 128x64 = 8x4 fragments (128 VGPR)
    float4 pa[2][4];          // A prefetch: depth-2, 16 floats (one row seg)
    float4 pb[4];             // B prefetch: depth-1

#define LOAD_A(set, kk)                                          \
    {                                                            \
        _Pragma("unroll")                                        \
        for (int v = 0; v < 4; ++v)                              \
            pa[set][v] = *(const float4*)(xp + (kk) + v * 4);    \
    }
#define LOAD_B(kk)                                               \
    {                                                            \
        _Pragma("unroll")                                        \
        for (int v = 0; v < 4; ++v)                              \
            pb[v] = *(const float4*)(wp + (kk) + v * 4);         \
    }
    // 4 float4 (16 floats) -> two bf16x8
#define CVT4(pv, s0, s1)                                                      \
    {                                                                         \
        s0[0]=f2bf(pv[0].x); s0[1]=f2bf(pv[0].y);                             \
        s0[2]=f2bf(pv[0].z); s0[3]=f2bf(pv[0].w);                             \
        s0[4]=f2bf(pv[1].x); s0[5]=f2bf(pv[1].y);                             \
        s0[6]=f2bf(pv[1].z); s0[7]=f2bf(pv[1].w);                             \
        s1[0]=f2bf(pv[2].x); s1[1]=f2bf(pv[2].y);                             \
        s1[2]=f2bf(pv[2].z); s1[3]=f2bf(pv[2].w);                             \
        s1[4]=f2bf(pv[3].x); s1[5]=f2bf(pv[3].y);                             \
        s1[6]=f2bf(pv[3].z); s1[7]=f2bf(pv[3].w);                             \
    }

    // ---- Prologue. FIFO order = consume order: A(0), B(0), A(1). ----
    LOAD_A(0, 0);
    LOAD_B(0);
    LOAD_A(1, BK);

    // ---- Main loop: R6-proven schedule, two relaxed barriers per iter ----
    #pragma unroll
    for (int t = 0; t < NK; ++t) {
        const int s = t & 1;

        // Convert tile t. CVT-A waits the oldest in-flight loads (A(t));
        // CVT-B waits B(t), which is older than A(t+1) -> A(t+1) stays
        // in flight across the barriers.
        bf16x8 sa0, sa1, sb0, sb1;
        CVT4(pa[s], sa0, sa1);
        CVT4(pb,    sb0, sb1);

        barrier_lds();   // all waves' prior frag ds_reads retired (lgkmcnt 0)
        *(bf16x8*)&As[srow * LDSS + scol]     = sa0;
        *(bf16x8*)&As[srow * LDSS + scol + 8] = sa1;
        *(bf16x8*)&Bs[srow * LDSS + scol]     = sb0;
        *(bf16x8*)&Bs[srow * LDSS + scol + 8] = sb1;
        barrier_lds();   // staged tile visible; vmcnt prefetches NOT drained

        // Refill in next-consume order: B(t+1) first, then A(t+2).
        if (t + 1 < NK) LOAD_B((t + 1) * BK);
        if (t + 2 < NK) LOAD_A(s, (t + 2) * BK);

        bf16x8 af[8], bfr[4];
        #pragma unroll
        for (int mi = 0; mi < 8; ++mi)
            af[mi] = *(const bf16x8*)&As[(mOff + mi * 16 + lrow) * LDSS + lk];
        #pragma unroll
        for (int ni = 0; ni < 4; ++ni)
            bfr[ni] = *(const bf16x8*)&Bs[(nOff + ni * 16 + lrow) * LDSS + lk];

        #pragma unroll
        for (int mi = 0; mi < 8; ++mi)
            #pragma unroll
            for (int ni = 0; ni < 4; ++ni)
                acc[mi][ni] = __builtin_amdgcn_mfma_f32_16x16x32_bf16(
                    af[mi], bfr[ni], acc[mi][ni], 0, 0, 0);
    }

#undef LOAD_A
#undef LOAD_B
#undef CVT4

    // Epilogue: C/D layout col = lane&15 (n), row = (lane>>4)*4 + r (m)
    const float scale = 0.04419417382415922f;  // 1/sqrt(512), LR_MUL = 1
    const int rbase = (lane >> 4) << 2;
    #pragma unroll
    for (int ni = 0; ni < 4; ++ni) {
        const int d  = nt * BN + nOff + ni * 16 + lrow;
        const float bv = bias[o * C_DIM + d];
        #pragma unroll
        for (int mi = 0; mi < 8; ++mi) {
            #pragma unroll
            for (int r2 = 0; r2 < 4; ++r2) {
                const int kr = mOff + mi * 16 + rbase + r2;   // batch index k
                out[((size_t)(kr * O_DIM + o) * J_DIM + jj) * C_DIM + d] =
                    acc[mi][ni][r2] * scale + bv;
            }
        }
    }
}

// Rows jj not present in idx keep their x values. With idx = arange(18) this
// kernel does no memory traffic (membership always true -> early exit).
__global__ void copy_nonsel(const float* __restrict__ x, const int* __restrict__ idx,
                            float* __restrict__ out)
{
    const int jj = blockIdx.x;
    const int o  = blockIdx.y;
    bool member = false;
    for (int t = 0; t < J_DIM; ++t) member = member || (idx[t] == jj);
    if (member) return;
    const int tid = threadIdx.x;
    for (int k = 0; k < KB; ++k) {
        const size_t base = ((size_t)(k * O_DIM + o) * J_DIM + jj) * C_DIM;
        for (int c = tid * 4; c < C_DIM; c += 256 * 4) {
            *(float4*)&out[base + c] = *(const float4*)&x[base + c];
        }
    }
}

extern "C" void kernel_launch(void* const* d_in, const int* in_sizes, int n_in,
                              void* d_out, int out_size, void* d_ws, size_t ws_size,
                              hipStream_t stream) {
    const float* x   = (const float*)d_in[0];
    const float* W   = (const float*)d_in[1];
    const float* b   = (const float*)d_in[2];
    const int*   idx = (const int*)d_in[3];
    float* out = (float*)d_out;

    // 1 mt * 2 nt * 18 j * 18 o = 648 blocks of 512 threads
    dirnet_gemm<<<dim3(2 * J_DIM * O_DIM), 512, 0, stream>>>(x, W, b, idx, out);
    copy_nonsel<<<dim3(J_DIM, O_DIM), 256, 0, stream>>>(x, idx, out);
}

// Round 5
// 364.556 us; speedup vs baseline: 1.0266x; 1.0185x over previous
//
#include <hip/hip_runtime.h>
#include <hip/hip_bf16.h>

// DirNet: out[k,o,idx[j],d] = SCALE * sum_i x[k,o,idx[j],i] * W[o,d,i] + b[o,d]
// Batched B^T GEMM, bf16 MFMA (16x16x32), fp32 accumulate.
// R11: VMEM-transaction attack. R6/R9/R10 invariance (time ~160us while HBM
// bytes, tile size, occupancy all changed 2-4x) points at TA/L1 line
// throughput: old lane map touched 64 distinct 64B lines per load instr
// (2 lanes/row, 16B pieces, rows 648KB/2KB apart) -> ~166k transactions/CU
// at ~0.5-1/cy = the whole runtime. Fix: lane map with 8 lanes/row covering
// 128B contiguous -> 8 rows x 2 lines = 16 transactions/instr (4x fewer).
// Everything else (256x256 tile, 512 thr, R6-proven 2-barrier relaxed
// schedule, A depth-2 / B depth-1 prefetch, XCD swizzle, epilogue) unchanged.

typedef __bf16  bf16x4  __attribute__((ext_vector_type(4)));
typedef __bf16  bf16x8  __attribute__((ext_vector_type(8)));
typedef float   floatx4 __attribute__((ext_vector_type(4)));

#define O_DIM 18
#define J_DIM 18
#define KB    256
#define C_DIM 512
#define BM    256
#define BN    256
#define BK    32
#define NK    (C_DIM / BK)   // 16 K-iterations
#define LDSS  40             // BK + 8 pad -> 80B stride, 2-way-free b128 reads

__device__ __forceinline__ __bf16 f2bf(float f) { return (__bf16)f; }

// Barrier that waits only LDS ops (lgkmcnt(0)), leaving global loads (vmcnt)
// in flight. 0xc07f = vmcnt 63 | expcnt 7 | lgkmcnt 0 (gfx9 encoding).
// Memory clobbers pin LDS op ordering across the barrier at compile time.
__device__ __forceinline__ void barrier_lds() {
    asm volatile("" ::: "memory");
    __builtin_amdgcn_s_waitcnt(0xc07f);
    __builtin_amdgcn_s_barrier();
    asm volatile("" ::: "memory");
}

__global__ __launch_bounds__(512, 2)
void dirnet_gemm(const float* __restrict__ x, const float* __restrict__ W,
                 const float* __restrict__ bias, const int* __restrict__ idx,
                 float* __restrict__ out)
{
    // XCD-aware decode. 648 blocks = 8 XCD x 81; nt fastest (x-tile shared by
    // the nt-pair -> co-XCD L2), then j-dense within o. Bijective: 8*81=648.
    const int id  = blockIdx.x;        // 0..647
    const int xcd = id & 7;
    const int q   = id >> 3;           // 0..80
    const int T   = xcd * 81 + q;      // 0..647, bijective
    const int o   = T / 36;
    const int rem = T - o * 36;
    const int j   = rem >> 1;
    const int nt  = rem & 1;
    const int jj  = idx[j];

    __shared__ __bf16 As[BM * LDSS];   // 20480 B
    __shared__ __bf16 Bs[BN * LDSS];   // 20480 B

    const int tid  = threadIdx.x;
    // NEW lane map: 8 lanes per row, each lane one float4 (16 B); a wave's
    // 64 lanes cover 8 rows x 128 B contiguous -> 16 L1 transactions/instr.
    const int rowA = tid >> 3;          // 0..63 (row within a 64-row band)
    const int colp = (tid & 7) << 2;    // float offset 0,4,...,28 in K-window

    // A row (band l): batch k = rowA + 64*l.
    const float* xp = x + ((size_t)(rowA * O_DIM + o) * J_DIM + jj) * C_DIM + colp;
    const size_t xRS = (size_t)64 * O_DIM * J_DIM * C_DIM;   // 64 batch rows
    // B row (band l): d = nt*BN + rowA + 64*l.
    const float* wp = W + ((size_t)(o * C_DIM + nt * BN + rowA)) * C_DIM + colp;
    const size_t wRS = (size_t)64 * C_DIM;                   // 64 W rows

    const int lane = tid & 63;
    const int wv   = tid >> 6;          // 0..7 waves, 2(M) x 4(N)
    const int mOff = (wv & 1) * 128;
    const int nOff = (wv >> 1) * 64;
    const int lrow = lane & 15;         // frag row (A: m, B: n)
    const int lk   = (lane >> 4) << 3;  // frag k offset (quad*8)

    floatx4 acc[8][4] = {};   // wave tile 128x64 = 8x4 fragments (128 VGPR)
    float4 pa[2][4];          // [set][band l]  A: depth-2
    float4 pb[4];             // [band l]       B: depth-1

#define LOAD_A(set, kk)                                          \
    {                                                            \
        _Pragma("unroll")                                        \
        for (int l = 0; l < 4; ++l)                              \
            pa[set][l] = *(const float4*)(xp + l * xRS + (kk));  \
    }
#define LOAD_B(kk)                                               \
    {                                                            \
        _Pragma("unroll")                                        \
        for (int l = 0; l < 4; ++l)                              \
            pb[l] = *(const float4*)(wp + l * wRS + (kk));       \
    }
    // float4 -> bf16x4 (8 B)
#define CVT1(pv, s0)                                             \
    {                                                            \
        s0[0] = f2bf(pv.x); s0[1] = f2bf(pv.y);                  \
        s0[2] = f2bf(pv.z); s0[3] = f2bf(pv.w);                  \
    }

    // ---- Prologue. FIFO order = consume order: A(0), B(0), A(1). ----
    LOAD_A(0, 0);
    LOAD_B(0);
    LOAD_A(1, BK);

    // ---- Main loop: R6-proven schedule, two relaxed barriers per iter ----
    #pragma unroll
    for (int t = 0; t < NK; ++t) {
        const int s = t & 1;

        // Convert tile t. CVT-A waits the oldest in-flight loads (A(t));
        // CVT-B waits B(t), older than A(t+1) -> A(t+1) stays in flight.
        bf16x4 sa[4], sb[4];
        #pragma unroll
        for (int l = 0; l < 4; ++l) CVT1(pa[s][l], sa[l]);
        #pragma unroll
        for (int l = 0; l < 4; ++l) CVT1(pb[l],    sb[l]);

        barrier_lds();   // all waves' prior frag ds_reads retired (lgkmcnt 0)
        #pragma unroll
        for (int l = 0; l < 4; ++l) {
            *(bf16x4*)&As[(rowA + 64 * l) * LDSS + colp] = sa[l];
            *(bf16x4*)&Bs[(rowA + 64 * l) * LDSS + colp] = sb[l];
        }
        barrier_lds();   // staged tile visible; vmcnt prefetches NOT drained

        // Refill in next-consume order: B(t+1) first, then A(t+2).
        if (t + 1 < NK) LOAD_B((t + 1) * BK);
        if (t + 2 < NK) LOAD_A(s, (t + 2) * BK);

        bf16x8 af[8], bfr[4];
        #pragma unroll
        for (int mi = 0; mi < 8; ++mi)
            af[mi] = *(const bf16x8*)&As[(mOff + mi * 16 + lrow) * LDSS + lk];
        #pragma unroll
        for (int ni = 0; ni < 4; ++ni)
            bfr[ni] = *(const bf16x8*)&Bs[(nOff + ni * 16 + lrow) * LDSS + lk];

        #pragma unroll
        for (int mi = 0; mi < 8; ++mi)
            #pragma unroll
            for (int ni = 0; ni < 4; ++ni)
                acc[mi][ni] = __builtin_amdgcn_mfma_f32_16x16x32_bf16(
                    af[mi], bfr[ni], acc[mi][ni], 0, 0, 0);
    }

#undef LOAD_A
#undef LOAD_B
#undef CVT1

    // Epilogue: C/D layout col = lane&15 (n), row = (lane>>4)*4 + r (m)
    const float scale = 0.04419417382415922f;  // 1/sqrt(512), LR_MUL = 1
    const int rbase = (lane >> 4) << 2;
    #pragma unroll
    for (int ni = 0; ni < 4; ++ni) {
        const int d  = nt * BN + nOff + ni * 16 + lrow;
        const float bv = bias[o * C_DIM + d];
        #pragma unroll
        for (int mi = 0; mi < 8; ++mi) {
            #pragma unroll
            for (int r2 = 0; r2 < 4; ++r2) {
                const int kr = mOff + mi * 16 + rbase + r2;   // batch index k
                out[((size_t)(kr * O_DIM + o) * J_DIM + jj) * C_DIM + d] =
                    acc[mi][ni][r2] * scale + bv;
            }
        }
    }
}

// Rows jj not present in idx keep their x values. With idx = arange(18) this
// kernel does no memory traffic (membership always true -> early exit).
__global__ void copy_nonsel(const float* __restrict__ x, const int* __restrict__ idx,
                            float* __restrict__ out)
{
    const int jj = blockIdx.x;
    const int o  = blockIdx.y;
    bool member = false;
    for (int t = 0; t < J_DIM; ++t) member = member || (idx[t] == jj);
    if (member) return;
    const int tid = threadIdx.x;
    for (int k = 0; k < KB; ++k) {
        const size_t base = ((size_t)(k * O_DIM + o) * J_DIM + jj) * C_DIM;
        for (int c = tid * 4; c < C_DIM; c += 256 * 4) {
            *(float4*)&out[base + c] = *(const float4*)&x[base + c];
        }
    }
}

extern "C" void kernel_launch(void* const* d_in, const int* in_sizes, int n_in,
                              void* d_out, int out_size, void* d_ws, size_t ws_size,
                              hipStream_t stream) {
    const float* x   = (const float*)d_in[0];
    const float* W   = (const float*)d_in[1];
    const float* b   = (const float*)d_in[2];
    const int*   idx = (const int*)d_in[3];
    float* out = (float*)d_out;

    // 1 mt * 2 nt * 18 j * 18 o = 648 blocks of 512 threads
    dirnet_gemm<<<dim3(2 * J_DIM * O_DIM), 512, 0, stream>>>(x, W, b, idx, out);
    copy_nonsel<<<dim3(J_DIM, O_DIM), 256, 0, stream>>>(x, idx, out);
}